// Round 1
// baseline (625.324 us; speedup 1.0000x reference)
//
#include <hip/hip_runtime.h>

#define NPIX 65536

// ws layout (float offsets)
#define WS_APLANE 0          // 3*65536
#define WS_ASUM   196608     // 65536
#define WS_KOFF   262144     // 10*65536
#define WS_KSUM   917504     // 10
#define WS_RING   917520     // 10*130
#define WS_KRAD   918832     // 10 ints
#define WS_U3     918848     // 3*65536
#define WS_MUX    1115456    // 3*65536
#define WS_MUY    1312064    // 3*65536
// total 1508672 floats ~= 6.04 MB

__global__ void repack(const float* __restrict__ A, float* __restrict__ ws) {
    int idx = blockIdx.x * 256 + threadIdx.x;
    float a0 = A[idx*3+0], a1 = A[idx*3+1], a2 = A[idx*3+2];
    ws[WS_APLANE + idx]          = a0;
    ws[WS_APLANE + NPIX + idx]   = a1;
    ws[WS_APLANE + 2*NPIX + idx] = a2;
    ws[WS_ASUM + idx] = a0 + a1 + a2;
}

// Build Koff[k][di+128][dj+128] = sig*ker (un-normalized), accumulate Chebyshev ring sums.
__global__ void build_kernels(const float* __restrict__ R_, const float* __restrict__ r_,
                              const float* __restrict__ a_, const float* __restrict__ b_,
                              const float* __restrict__ w_, float* __restrict__ ws) {
    __shared__ float rs[132];
    int k = blockIdx.x >> 8;
    int i = blockIdx.x & 255;
    int j = threadIdx.x;
    if (threadIdx.x < 132) rs[threadIdx.x] = 0.0f;
    __syncthreads();
    float R = R_[0];
    float denom = (R + 15.0f) * r_[k];
    int di = i - 128, dj = j - 128;
    float D  = sqrtf((float)(di*di + dj*dj));
    float Dk = D / denom;
    float ker = 0.0f;
    #pragma unroll
    for (int t = 0; t < 3; ++t) {
        float d = Dk - a_[k*3+t];
        ker += b_[k*3+t] * expf(-((d*d) / w_[k*3+t]));
    }
    float sig = 0.5f * (tanhf(-(Dk - 1.0f) * 5.0f) + 1.0f);
    float v = sig * ker;
    ws[WS_KOFF + k*NPIX + i*256 + j] = v;
    int adi = di < 0 ? -di : di;
    int adj = dj < 0 ? -dj : dj;
    int ring = adi > adj ? adi : adj;   // 0..128
    atomicAdd(&rs[ring], v);
    __syncthreads();
    if (threadIdx.x < 130) {
        float sv = rs[threadIdx.x];
        if (sv != 0.0f) atomicAdd(&ws[WS_RING + k*130 + threadIdx.x], sv);
    }
}

// Per-kernel: total sum (normalizer) + smallest radius with relative tail <= 1e-6.
__global__ void finalize_kernels(float* __restrict__ ws) {
    int k = threadIdx.x;
    if (k >= 10) return;
    const float* rs = &ws[WS_RING + k*130];
    float total = 0.0f;
    for (int ring = 0; ring <= 128; ++ring) total += rs[ring];
    float tol = 1e-6f * total;
    float tail = 0.0f;
    int rad = 1;
    for (int ring = 128; ring >= 1; --ring) {
        tail += rs[ring];
        if (tail > tol) { rad = ring; break; }
    }
    if (rad > 127) rad = 127;
    if (rad < 1)   rad = 1;
    ws[WS_KSUM + k] = total;
    ((int*)ws)[WS_KRAD + k] = rad;
}

// Direct circular convolution (adaptive radius) + growth + per-channel sum -> U3 plane.
// Channel c uses kernels {3c,3c+1,3c+2} (+9 for c==0); all read A-plane c.
template<int NK>
__global__ void conv_growth(float* __restrict__ ws, const float* __restrict__ m_,
                            const float* __restrict__ s_, const float* __restrict__ h_,
                            int c_base) {
    __shared__ float row[256];
    int c = c_base + (blockIdx.x >> 8);
    int x = blockIdx.x & 255;
    int y = threadIdx.x;
    int ks[4];
    ks[0] = c*3; ks[1] = c*3+1; ks[2] = c*3+2; ks[3] = 9;
    const int* krad = (const int*)ws + WS_KRAD;
    int rad = 1;
    #pragma unroll
    for (int kk = 0; kk < NK; ++kk) { int rr = krad[ks[kk]]; if (rr > rad) rad = rr; }
    const float* aplane = ws + WS_APLANE + c*NPIX;
    const float* k0 = ws + WS_KOFF + ks[0]*NPIX;
    const float* k1 = ws + WS_KOFF + ks[1]*NPIX;
    const float* k2 = ws + WS_KOFF + ks[2]*NPIX;
    const float* k3 = ws + WS_KOFF + 9*NPIX;
    float acc0 = 0.f, acc1 = 0.f, acc2 = 0.f, acc3 = 0.f;
    for (int di = -rad; di <= rad; ++di) {
        int sx = (x - di) & 255;
        __syncthreads();
        row[y] = aplane[sx*256 + y];
        __syncthreads();
        const float* r0 = k0 + (di+128)*256;
        const float* r1 = k1 + (di+128)*256;
        const float* r2 = k2 + (di+128)*256;
        const float* r3 = k3 + (di+128)*256;
        for (int dj = -rad; dj <= rad; ++dj) {
            float av = row[(y - dj) & 255];
            int col = dj + 128;
            acc0 = fmaf(av, r0[col], acc0);
            acc1 = fmaf(av, r1[col], acc1);
            acc2 = fmaf(av, r2[col], acc2);
            if (NK == 4) acc3 = fmaf(av, r3[col], acc3);
        }
    }
    float accs[4] = {acc0, acc1, acc2, acc3};
    float outv = 0.0f;
    #pragma unroll
    for (int kk = 0; kk < NK; ++kk) {
        int k = ks[kk];
        float U = accs[kk] / ws[WS_KSUM + k];
        float z = (U - m_[k]) / s_[k];
        float g = expf(-0.5f * z * z) * 2.0f - 1.0f;
        outv += h_[k] * g;
    }
    ws[WS_U3 + c*NPIX + x*256 + y] = outv;
}

__device__ inline void sobel_at(const float* __restrict__ p, int x, int y,
                                float& gy, float& gx) {
    float v[3][3];
    #pragma unroll
    for (int ii = -1; ii <= 1; ++ii)
        #pragma unroll
        for (int jj = -1; jj <= 1; ++jj) {
            int xx = x + ii, yy = y + jj;
            v[ii+1][jj+1] = (xx < 0 || xx > 255 || yy < 0 || yy > 255)
                            ? 0.0f : p[xx*256 + yy];
        }
    // conv with _KY (d=0 component): (row i-1 smoothed) - (row i+1 smoothed)
    gy = (v[0][0] + 2.0f*v[0][1] + v[0][2]) - (v[2][0] + 2.0f*v[2][1] + v[2][2]);
    // conv with _KX (d=1 component): (col j-1 smoothed) - (col j+1 smoothed)
    gx = (v[0][0] + 2.0f*v[1][0] + v[2][0]) - (v[0][2] + 2.0f*v[1][2] + v[2][2]);
}

__global__ void compute_mu(float* __restrict__ ws) {
    int x = blockIdx.x;
    int y = threadIdx.x;
    float gyA, gxA;
    sobel_at(ws + WS_ASUM, x, y, gyA, gxA);
    #pragma unroll
    for (int c = 0; c < 3; ++c) {
        float gy, gx;
        sobel_at(ws + WS_U3 + c*NPIX, x, y, gy, gx);
        float a = ws[WS_APLANE + c*NPIX + x*256 + y];
        float al = (a / 3.0f); al = al * al;
        al = fminf(fmaxf(al, 0.0f), 1.0f);
        float F0 = gy * (1.0f - al) - gyA * al;
        float F1 = gx * (1.0f - al) - gxA * al;
        float d0 = fminf(fmaxf(0.2f * F0, -4.35f), 4.35f);
        float d1 = fminf(fmaxf(0.2f * F1, -4.35f), 4.35f);
        float mx = fminf(fmaxf((float)x + 0.5f + d0, 0.65f), 255.35f);
        float my = fminf(fmaxf((float)y + 0.5f + d1, 0.65f), 255.35f);
        ws[WS_MUX + c*NPIX + x*256 + y] = mx;
        ws[WS_MUY + c*NPIX + x*256 + y] = my;
    }
}

__global__ void rt_apply(const float* __restrict__ ws, float* __restrict__ out) {
    int b = blockIdx.x;          // 768 = 3 channels * 256 rows
    int c = b >> 8;
    int x = b & 255;
    int y = threadIdx.x;
    const float* ap = ws + WS_APLANE + c*NPIX;
    const float* mx = ws + WS_MUX + c*NPIX;
    const float* my = ws + WS_MUY + c*NPIX;
    float px = (float)x + 0.5f, py = (float)y + 0.5f;
    float acc = 0.0f;
    #pragma unroll
    for (int dx = -5; dx <= 5; ++dx) {
        int sx = (x - dx) & 255;
        int rowb = sx * 256;
        #pragma unroll
        for (int dy = -5; dy <= 5; ++dy) {
            int sy = (y - dy) & 255;
            float a  = ap[rowb + sy];
            float ax = 1.15f - fabsf(px - mx[rowb + sy]);
            float ay = 1.15f - fabsf(py - my[rowb + sy]);
            ax = fminf(fmaxf(ax, 0.0f), 1.0f);
            ay = fminf(fmaxf(ay, 0.0f), 1.0f);
            acc = fmaf(a, ax * ay, acc);
        }
    }
    out[(x*256 + y)*3 + c] = acc * (1.0f / (4.0f * 0.65f * 0.65f));
}

extern "C" void kernel_launch(void* const* d_in, const int* in_sizes, int n_in,
                              void* d_out, int out_size, void* d_ws, size_t ws_size,
                              hipStream_t stream) {
    const float* A = (const float*)d_in[0];
    const float* R = (const float*)d_in[1];
    const float* r = (const float*)d_in[2];
    const float* m = (const float*)d_in[3];
    const float* s = (const float*)d_in[4];
    const float* h = (const float*)d_in[5];
    const float* a = (const float*)d_in[6];
    const float* b = (const float*)d_in[7];
    const float* w = (const float*)d_in[8];
    float* ws  = (float*)d_ws;
    float* out = (float*)d_out;

    // zero ksum + ring sums (+krad) — ws is poisoned each call
    hipMemsetAsync((char*)d_ws + (size_t)WS_KSUM*sizeof(float), 0,
                   (size_t)(WS_U3 - WS_KSUM)*sizeof(float), stream);

    repack<<<256, 256, 0, stream>>>(A, ws);
    build_kernels<<<2560, 256, 0, stream>>>(R, r, a, b, w, ws);
    finalize_kernels<<<1, 64, 0, stream>>>(ws);
    conv_growth<4><<<256, 256, 0, stream>>>(ws, m, s, h, 0);
    conv_growth<3><<<512, 256, 0, stream>>>(ws, m, s, h, 1);
    compute_mu<<<256, 256, 0, stream>>>(ws);
    rt_apply<<<768, 256, 0, stream>>>(ws, out);
}

// Round 2
// 229.682 us; speedup vs baseline: 2.7226x; 2.7226x over previous
//
#include <hip/hip_runtime.h>

#define NPIX 65536

// ws layout (float offsets). KOFF region (10 planes) is DEAD after conv_v2,
// so U3/MUX/MUY are overlaid onto it for the post-conv stages.
#define WS_APLANE 0                        // 3 planes
#define WS_ASUM   (3*NPIX)                 // 1 plane
#define WS_KOFF   (4*NPIX)                 // 10 planes (conv stage)
#define WS_U3     (4*NPIX)                 // planes 0-2 of KOFF (post-conv)
#define WS_MUX    (7*NPIX)                 // planes 3-5 of KOFF
#define WS_MUY    (10*NPIX)                // planes 6-8 of KOFF
#define WS_UACC   (14*NPIX)                // 10 planes of per-kernel partial U
#define WS_KSUM   (24*NPIX)                // 10
#define WS_RING   (24*NPIX+16)             // 10*130 -> 1312 slot
#define WS_KRAD   (24*NPIX+16+1312)        // 10 ints
#define WS_END    (24*NPIX+16+1312+16)

#define SSEG 8   // di-range split factor for conv occupancy

__global__ void repack(const float* __restrict__ A, float* __restrict__ ws) {
    int idx = blockIdx.x * 256 + threadIdx.x;
    float a0 = A[idx*3+0], a1 = A[idx*3+1], a2 = A[idx*3+2];
    ws[WS_APLANE + idx]          = a0;
    ws[WS_APLANE + NPIX + idx]   = a1;
    ws[WS_APLANE + 2*NPIX + idx] = a2;
    ws[WS_ASUM + idx] = a0 + a1 + a2;
}

// Build Koff[k][di+128][dj+128] = sig*ker (un-normalized), accumulate Chebyshev ring sums.
__global__ void build_kernels(const float* __restrict__ R_, const float* __restrict__ r_,
                              const float* __restrict__ a_, const float* __restrict__ b_,
                              const float* __restrict__ w_, float* __restrict__ ws) {
    __shared__ float rs[132];
    int k = blockIdx.x >> 8;
    int i = blockIdx.x & 255;
    int j = threadIdx.x;
    if (threadIdx.x < 132) rs[threadIdx.x] = 0.0f;
    __syncthreads();
    float R = R_[0];
    float denom = (R + 15.0f) * r_[k];
    int di = i - 128, dj = j - 128;
    float D  = sqrtf((float)(di*di + dj*dj));
    float Dk = D / denom;
    float ker = 0.0f;
    #pragma unroll
    for (int t = 0; t < 3; ++t) {
        float d = Dk - a_[k*3+t];
        ker += b_[k*3+t] * expf(-((d*d) / w_[k*3+t]));
    }
    float sig = 0.5f * (tanhf(-(Dk - 1.0f) * 5.0f) + 1.0f);
    float v = sig * ker;
    ws[WS_KOFF + k*NPIX + i*256 + j] = v;
    int adi = di < 0 ? -di : di;
    int adj = dj < 0 ? -dj : dj;
    int ring = adi > adj ? adi : adj;   // 0..128
    atomicAdd(&rs[ring], v);
    __syncthreads();
    if (threadIdx.x < 130) {
        float sv = rs[threadIdx.x];
        if (sv != 0.0f) atomicAdd(&ws[WS_RING + k*130 + threadIdx.x], sv);
    }
}

// Per-kernel: total sum (normalizer) + smallest radius with relative tail <= 1e-6.
__global__ void finalize_kernels(float* __restrict__ ws) {
    int k = threadIdx.x;
    if (k >= 10) return;
    const float* rs = &ws[WS_RING + k*130];
    float total = 0.0f;
    for (int ring = 0; ring <= 128; ++ring) total += rs[ring];
    float tol = 1e-6f * total;
    float tail = 0.0f;
    int rad = 1;
    for (int ring = 128; ring >= 1; --ring) {
        tail += rs[ring];
        if (tail > tol) { rad = ring; break; }
    }
    if (rad > 127) rad = 127;
    if (rad < 1)   rad = 1;
    ws[WS_KSUM + k] = total;
    ((int*)ws)[WS_KRAD + k] = rad;
}

// Padded LDS index: stride-4 lane pattern would be 8-way bank conflicted; +j>>5 fixes it.
#define B(P) buf[(P) + ((P)>>5)]

// Direct circular conv, di-segmented for occupancy. Each wave handles one output
// row; each lane computes 4 adjacent y-outputs with a register sliding window
// (1 LDS read per tap). Partial per-kernel sums -> atomicAdd into UACC planes.
template<int NK>
__device__ __forceinline__ void conv_inner(
    const float* __restrict__ ws, const float* __restrict__ aplane,
    float* __restrict__ buf, float acc[4][4],
    int x, int y0, int lane, int rad, int di_lo, int di_hi, int kbase)
{
    for (int di = di_lo; di < di_hi; ++di) {
        int srow = (x - di) & 255;
        const float* arow = aplane + srow*256;
        #pragma unroll
        for (int t = 0; t < 8; ++t) {
            int j = t*64 + lane;
            int pj = j + (j>>5);
            buf[pj] = arow[(j - 128) & 255];
        }
        // per-wave private LDS buffer; DS pipe is in-order within a wave,
        // so no barrier needed between fill and read.
        const float* krow0 = ws + WS_KOFF + (kbase+0)*NPIX + (di+128)*256 + 128;
        const float* krow1 = ws + WS_KOFF + (kbase+1)*NPIX + (di+128)*256 + 128;
        const float* krow2 = ws + WS_KOFF + (kbase+2)*NPIX + (di+128)*256 + 128;
        const float* krow3 = ws + WS_KOFF + 9*NPIX        + (di+128)*256 + 128;

        #define FMAS(DJ, W0, W1, W2, W3) do {                                   \
            float kv0 = krow0[(DJ)];                                            \
            acc[0][0] = fmaf(kv0,(W0),acc[0][0]);                               \
            acc[0][1] = fmaf(kv0,(W1),acc[0][1]);                               \
            acc[0][2] = fmaf(kv0,(W2),acc[0][2]);                               \
            acc[0][3] = fmaf(kv0,(W3),acc[0][3]);                               \
            float kv1 = krow1[(DJ)];                                            \
            acc[1][0] = fmaf(kv1,(W0),acc[1][0]);                               \
            acc[1][1] = fmaf(kv1,(W1),acc[1][1]);                               \
            acc[1][2] = fmaf(kv1,(W2),acc[1][2]);                               \
            acc[1][3] = fmaf(kv1,(W3),acc[1][3]);                               \
            float kv2 = krow2[(DJ)];                                            \
            acc[2][0] = fmaf(kv2,(W0),acc[2][0]);                               \
            acc[2][1] = fmaf(kv2,(W1),acc[2][1]);                               \
            acc[2][2] = fmaf(kv2,(W2),acc[2][2]);                               \
            acc[2][3] = fmaf(kv2,(W3),acc[2][3]);                               \
            if (NK == 4) {                                                      \
                float kv3 = krow3[(DJ)];                                        \
                acc[3][0] = fmaf(kv3,(W0),acc[3][0]);                           \
                acc[3][1] = fmaf(kv3,(W1),acc[3][1]);                           \
                acc[3][2] = fmaf(kv3,(W2),acc[3][2]);                           \
                acc[3][3] = fmaf(kv3,(W3),acc[3][3]);                           \
            }                                                                   \
        } while (0)

        int p = y0 + 128 + rad;     // logical index of window reg a0 at dj=-rad
        float a0 = B(p), a1 = B(p+1), a2 = B(p+2), a3 = B(p+3);
        int dj = -rad;
        for (; dj + 3 <= rad; dj += 4) {
            FMAS(dj,   a0, a1, a2, a3);
            float n1 = B(p-1);
            FMAS(dj+1, n1, a0, a1, a2);
            float n2 = B(p-2);
            FMAS(dj+2, n2, n1, a0, a1);
            float n3 = B(p-3);
            FMAS(dj+3, n3, n2, n1, a0);
            float n4 = B(p-4);
            a0 = n4; a1 = n3; a2 = n2; a3 = n1;
            p -= 4;
        }
        for (; dj <= rad; ++dj) {
            FMAS(dj, a0, a1, a2, a3);
            float nw = B(p-1);
            a3 = a2; a2 = a1; a1 = a0; a0 = nw; --p;
        }
        #undef FMAS
    }
}

__global__ __launch_bounds__(256) void conv_v2(float* __restrict__ ws) {
    __shared__ float lds[4*528];
    int bid = blockIdx.x;
    int seg = bid / 192;
    int rem = bid - seg*192;
    int c   = rem >> 6;
    int rg  = rem & 63;
    int sub  = threadIdx.x >> 6;
    int lane = threadIdx.x & 63;
    int x  = rg*4 + sub;
    int y0 = lane*4;
    const int* krad = (const int*)ws + WS_KRAD;
    int nk = (c == 0) ? 4 : 3;
    int kbase = c*3;
    int rad = 1;
    for (int kk = 0; kk < nk; ++kk) {
        int k = (kk == 3) ? 9 : kbase + kk;
        int rr = krad[k];
        rad = rr > rad ? rr : rad;
    }
    int nsteps = 2*rad + 1;
    int chunk = (nsteps + SSEG - 1) / SSEG;
    int di_lo = -rad + seg*chunk;
    int di_hi = di_lo + chunk;
    if (di_hi > rad + 1) di_hi = rad + 1;
    if (di_lo >= di_hi) return;

    float* buf = &lds[sub*528];
    const float* aplane = ws + WS_APLANE + c*NPIX;
    float acc[4][4];
    #pragma unroll
    for (int i = 0; i < 4; ++i)
        #pragma unroll
        for (int j = 0; j < 4; ++j) acc[i][j] = 0.0f;

    if (c == 0)
        conv_inner<4>(ws, aplane, buf, acc, x, y0, lane, rad, di_lo, di_hi, kbase);
    else
        conv_inner<3>(ws, aplane, buf, acc, x, y0, lane, rad, di_lo, di_hi, kbase);

    float* uacc = ws + WS_UACC;
    int obase = x*256 + y0;
    for (int kk = 0; kk < nk; ++kk) {
        int k = (kk == 3) ? 9 : kbase + kk;
        float* up = uacc + k*NPIX + obase;
        atomicAdd(up + 0, acc[kk][0]);
        atomicAdd(up + 1, acc[kk][1]);
        atomicAdd(up + 2, acc[kk][2]);
        atomicAdd(up + 3, acc[kk][3]);
    }
}

// Normalize, growth nonlinearity, per-channel kernel-group sum -> U3 planes.
__global__ void growth_k(float* __restrict__ ws, const float* __restrict__ m_,
                         const float* __restrict__ s_, const float* __restrict__ h_) {
    int idx = blockIdx.x*256 + threadIdx.x;
    const float* uacc = ws + WS_UACC;
    #pragma unroll
    for (int c = 0; c < 3; ++c) {
        int nk = (c == 0) ? 4 : 3;
        float outv = 0.0f;
        for (int kk = 0; kk < nk; ++kk) {
            int k = (kk == 3) ? 9 : c*3 + kk;
            float U = uacc[k*NPIX + idx] / ws[WS_KSUM + k];
            float z = (U - m_[k]) / s_[k];
            outv += h_[k] * (expf(-0.5f*z*z)*2.0f - 1.0f);
        }
        ws[WS_U3 + c*NPIX + idx] = outv;
    }
}

__device__ inline void sobel_at(const float* __restrict__ p, int x, int y,
                                float& gy, float& gx) {
    float v[3][3];
    #pragma unroll
    for (int ii = -1; ii <= 1; ++ii)
        #pragma unroll
        for (int jj = -1; jj <= 1; ++jj) {
            int xx = x + ii, yy = y + jj;
            v[ii+1][jj+1] = (xx < 0 || xx > 255 || yy < 0 || yy > 255)
                            ? 0.0f : p[xx*256 + yy];
        }
    gy = (v[0][0] + 2.0f*v[0][1] + v[0][2]) - (v[2][0] + 2.0f*v[2][1] + v[2][2]);
    gx = (v[0][0] + 2.0f*v[1][0] + v[2][0]) - (v[0][2] + 2.0f*v[1][2] + v[2][2]);
}

__global__ void compute_mu(float* __restrict__ ws) {
    int x = blockIdx.x;
    int y = threadIdx.x;
    float gyA, gxA;
    sobel_at(ws + WS_ASUM, x, y, gyA, gxA);
    #pragma unroll
    for (int c = 0; c < 3; ++c) {
        float gy, gx;
        sobel_at(ws + WS_U3 + c*NPIX, x, y, gy, gx);
        float a = ws[WS_APLANE + c*NPIX + x*256 + y];
        float al = (a / 3.0f); al = al * al;
        al = fminf(fmaxf(al, 0.0f), 1.0f);
        float F0 = gy * (1.0f - al) - gyA * al;
        float F1 = gx * (1.0f - al) - gxA * al;
        float d0 = fminf(fmaxf(0.2f * F0, -4.35f), 4.35f);
        float d1 = fminf(fmaxf(0.2f * F1, -4.35f), 4.35f);
        float mx = fminf(fmaxf((float)x + 0.5f + d0, 0.65f), 255.35f);
        float my = fminf(fmaxf((float)y + 0.5f + d1, 0.65f), 255.35f);
        ws[WS_MUX + c*NPIX + x*256 + y] = mx;
        ws[WS_MUY + c*NPIX + x*256 + y] = my;
    }
}

__global__ void rt_apply(const float* __restrict__ ws, float* __restrict__ out) {
    int b = blockIdx.x;          // 768 = 3 channels * 256 rows
    int c = b >> 8;
    int x = b & 255;
    int y = threadIdx.x;
    const float* ap = ws + WS_APLANE + c*NPIX;
    const float* mx = ws + WS_MUX + c*NPIX;
    const float* my = ws + WS_MUY + c*NPIX;
    float px = (float)x + 0.5f, py = (float)y + 0.5f;
    float acc = 0.0f;
    #pragma unroll
    for (int dx = -5; dx <= 5; ++dx) {
        int sx = (x - dx) & 255;
        int rowb = sx * 256;
        #pragma unroll
        for (int dy = -5; dy <= 5; ++dy) {
            int sy = (y - dy) & 255;
            float a  = ap[rowb + sy];
            float ax = 1.15f - fabsf(px - mx[rowb + sy]);
            float ay = 1.15f - fabsf(py - my[rowb + sy]);
            ax = fminf(fmaxf(ax, 0.0f), 1.0f);
            ay = fminf(fmaxf(ay, 0.0f), 1.0f);
            acc = fmaf(a, ax * ay, acc);
        }
    }
    out[(x*256 + y)*3 + c] = acc * (1.0f / (4.0f * 0.65f * 0.65f));
}

extern "C" void kernel_launch(void* const* d_in, const int* in_sizes, int n_in,
                              void* d_out, int out_size, void* d_ws, size_t ws_size,
                              hipStream_t stream) {
    const float* A = (const float*)d_in[0];
    const float* R = (const float*)d_in[1];
    const float* r = (const float*)d_in[2];
    const float* m = (const float*)d_in[3];
    const float* s = (const float*)d_in[4];
    const float* h = (const float*)d_in[5];
    const float* a = (const float*)d_in[6];
    const float* b = (const float*)d_in[7];
    const float* w = (const float*)d_in[8];
    float* ws  = (float*)d_ws;
    float* out = (float*)d_out;

    // zero UACC + KSUM + RING + KRAD (ws is re-poisoned before every call)
    hipMemsetAsync((char*)d_ws + (size_t)WS_UACC*sizeof(float), 0,
                   (size_t)(WS_END - WS_UACC)*sizeof(float), stream);

    repack<<<256, 256, 0, stream>>>(A, ws);
    build_kernels<<<2560, 256, 0, stream>>>(R, r, a, b, w, ws);
    finalize_kernels<<<1, 64, 0, stream>>>(ws);
    conv_v2<<<SSEG*192, 256, 0, stream>>>(ws);
    growth_k<<<256, 256, 0, stream>>>(ws, m, s, h);
    compute_mu<<<256, 256, 0, stream>>>(ws);
    rt_apply<<<768, 256, 0, stream>>>(ws, out);
}